// Round 1
// baseline (541.085 us; speedup 1.0000x reference)
//
#include <hip/hip_runtime.h>

// Problem: B=16, L=4096, D=1024
//   out[b,l,d] = S[b,l,d] + sum_mod outmod[b,d]
//   outmod = ((feat @ Wkv^T + bkv) @ Wv^T + bv) @ Wo^T + bo
// dins: image=2048, audio=1024, text=768

#define B_ 16
#define L_ 4096
#define D_ 1024

typedef float v4f __attribute__((ext_vector_type(4)));

struct StageArgs {
    const float* x[3];   // [B, K[m]]
    const float* W[3];   // [D, K[m]]
    const float* bias[3];// [D]
    float*       y[3];   // [B, D]
    int          K[3];
};

// Fused across modalities: 3 * 16384 waves, one wave per (m, b, d) dot.
// wid>>14 = m ; (wid>>10)&15 = b ; wid&1023 = d
__global__ __launch_bounds__(256) void gemv_stage(StageArgs a) {
    int wid  = (blockIdx.x * 256 + threadIdx.x) >> 6;
    int lane = threadIdx.x & 63;
    int m = wid >> 14;
    int r = wid & 16383;
    int bb = r >> 10;
    int d  = r & 1023;
    int K = a.K[m];

    const float* xr = a.x[m] + bb * K;
    const float* wr = a.W[m] + (size_t)d * K;

    float sum = 0.f;
    for (int k = lane * 4; k < K; k += 256) {
        float4 xv = *(const float4*)(xr + k);
        float4 wv = *(const float4*)(wr + k);
        sum += xv.x * wv.x + xv.y * wv.y + xv.z * wv.z + xv.w * wv.w;
    }
    for (int off = 32; off; off >>= 1) sum += __shfl_xor(sum, off, 64);

    if (lane == 0) a.y[m][(bb << 10) + d] = sum + a.bias[m][d];
}

struct Stage3Args {
    const float* v0; const float* v1; const float* v2;   // [B, D] each
    const float* W0; const float* W1; const float* W2;   // [D, D] each
    const float* b0; const float* b1; const float* b2;   // [D]
    float* delta;                                        // [B, D]
};

// 16384 waves; one wave computes delta[b,d] = sum_m dot(v_m[b,:], Wo_m[d,:]) + biases
__global__ __launch_bounds__(256) void gemv_stage3(Stage3Args a) {
    int wid  = (blockIdx.x * 256 + threadIdx.x) >> 6;
    int lane = threadIdx.x & 63;
    int bb = wid >> 10;
    int d  = wid & 1023;

    const float* xs[3] = { a.v0 + (bb << 10), a.v1 + (bb << 10), a.v2 + (bb << 10) };
    const float* ws[3] = { a.W0 + ((size_t)d << 10), a.W1 + ((size_t)d << 10),
                           a.W2 + ((size_t)d << 10) };
    float sum = 0.f;
    #pragma unroll
    for (int m = 0; m < 3; ++m) {
        const float* xr = xs[m];
        const float* wr = ws[m];
        #pragma unroll
        for (int k = lane * 4; k < 1024; k += 256) {
            float4 xv = *(const float4*)(xr + k);
            float4 wv = *(const float4*)(wr + k);
            sum += xv.x * wv.x + xv.y * wv.y + xv.z * wv.z + xv.w * wv.w;
        }
    }
    for (int off = 32; off; off >>= 1) sum += __shfl_xor(sum, off, 64);

    if (lane == 0)
        a.delta[(bb << 10) + d] = sum + a.b0[d] + a.b1[d] + a.b2[d];
}

// out[b,l,d] = S[b,l,d] + delta[b,d]
// Column-stationary mapping: each thread owns one (b, d4) float4 column and
// walks 32 consecutive l rows. delta is loaded ONCE per thread (register-
// resident); the hot loop is a pure nontemporal load->add->store stream.
// Wave lanes cover 64 consecutive d4 -> 1 KB coalesced per access.
// Grid: 2048 blocks * 256 threads = 524288 threads = 16 b * 128 chunks * 256 d4.
__global__ __launch_bounds__(256) void add_bcast(const v4f* __restrict__ S,
                                                 const v4f* __restrict__ delta,
                                                 v4f* __restrict__ out) {
    int tid   = blockIdx.x * 256 + threadIdx.x;
    int d4    = tid & 255;          // float4 column within D
    int chunk = (tid >> 8) & 127;   // which 32-row chunk of L
    int b     = tid >> 15;          // batch

    v4f dl = delta[(b << 8) + d4];

    // flat float4 index: b*(L*D/4) + l*(D/4) + d4 = (b<<20) + (l<<8) + d4
    size_t base = ((size_t)b << 20) + ((size_t)chunk << 13) + (size_t)d4;

    #pragma unroll 8
    for (int j = 0; j < 32; ++j) {
        size_t idx = base + ((size_t)j << 8);
        v4f s = __builtin_nontemporal_load(S + idx);
        __builtin_nontemporal_store(s + dl, out + idx);
    }
}

extern "C" void kernel_launch(void* const* d_in, const int* in_sizes, int n_in,
                              void* d_out, int out_size, void* d_ws, size_t ws_size,
                              hipStream_t stream) {
    const float* S = (const float*)d_in[0];

    const int dins[3] = {2048, 1024, 768};
    const float *feat[3], *Wkv[3], *bkv[3], *Wv[3], *bv[3], *Wo[3], *bo[3];
    for (int m = 0; m < 3; ++m) {
        int base = 1 + m * 7;
        feat[m] = (const float*)d_in[base + 0];
        Wkv[m]  = (const float*)d_in[base + 1];
        bkv[m]  = (const float*)d_in[base + 2];
        Wv[m]   = (const float*)d_in[base + 3];
        bv[m]   = (const float*)d_in[base + 4];
        Wo[m]   = (const float*)d_in[base + 5];
        bo[m]   = (const float*)d_in[base + 6];
    }

    float* ws = (float*)d_ws;
    const int BD = B_ * D_;
    float* kv[3]  = {ws, ws + BD, ws + 2 * BD};
    float* v[3]   = {ws + 3 * BD, ws + 4 * BD, ws + 5 * BD};
    float* delta  = ws + 6 * BD;

    // Stage 1: kv[m] = feat[m] @ Wkv[m]^T + bkv[m]   (3*16384 waves)
    StageArgs s1;
    for (int m = 0; m < 3; ++m) {
        s1.x[m] = feat[m]; s1.W[m] = Wkv[m]; s1.bias[m] = bkv[m];
        s1.y[m] = kv[m];   s1.K[m] = dins[m];
    }
    gemv_stage<<<12288, 256, 0, stream>>>(s1);

    // Stage 2: v[m] = kv[m] @ Wv[m]^T + bv[m]
    StageArgs s2;
    for (int m = 0; m < 3; ++m) {
        s2.x[m] = kv[m]; s2.W[m] = Wv[m]; s2.bias[m] = bv[m];
        s2.y[m] = v[m];  s2.K[m] = D_;
    }
    gemv_stage<<<12288, 256, 0, stream>>>(s2);

    // Stage 3: delta = sum_m (v[m] @ Wo[m]^T + bo[m])   (16384 waves)
    Stage3Args s3 = { v[0], v[1], v[2], Wo[0], Wo[1], Wo[2], bo[0], bo[1], bo[2], delta };
    gemv_stage3<<<4096, 256, 0, stream>>>(s3);

    // Broadcast add: column-stationary streaming kernel
    add_bcast<<<2048, 256, 0, stream>>>((const v4f*)S, (const v4f*)delta,
                                        (v4f*)d_out);
}